// Round 4
// baseline (507.757 us; speedup 1.0000x reference)
//
#include <hip/hip_runtime.h>

// ---------------------------------------------------------------------------
// RNNModel: 3-layer tanh RNN (B=128, T=512, IN=768, H=64) + FC(64->1)
// K0: pack_wih — one-shot Wih f32 -> fragment-ordered f16 (96 KB in ws).
// K1: MFMA f16 GEMM, LDS-free: wave = 16x64 C-tile, depth-4 A prefetch,
//     depth-2 packed-B prefetch (B is L2-resident).  R4.
// K2: fused recurrence. R4: 4 batches per block (768 thr, 12 waves, grid 32).
//     wave w: layer g = w>>2, batch bi = w&3 -> each SIMD gets 3 waves with
//     independent dependency chains (was 1 wave/SIMD, fully latency-exposed).
//     Epochs of 16 steps per barrier; x-part once per epoch via MFMA; biases
//     folded into xb; per-step chain: 8 b128 rc reads -> 32 fdot2 -> tanh.
// ---------------------------------------------------------------------------

typedef __fp16 h2_t __attribute__((ext_vector_type(2)));
typedef __fp16 h8_t __attribute__((ext_vector_type(8)));
typedef float  f4_t __attribute__((ext_vector_type(4)));

union F4H  { float4 f; h2_t h[4]; };
union F4H8 { float4 f; h8_t h8; h2_t h2[4]; };
union H8U  { h2_t h2[4]; h8_t h8; };

__device__ __forceinline__ float fdot2(h2_t a, h2_t b, float c) {
    return __builtin_amdgcn_fdot2(a, b, c, false);
}
__device__ __forceinline__ h2_t pack_h2(float x, float y) {
    return __builtin_amdgcn_cvt_pkrtz(x, y);
}
__device__ __forceinline__ float tanh_fast(float x) {
    float e = __expf(2.0f * x);
    return 1.0f - 2.0f * __builtin_amdgcn_rcpf(e + 1.0f);
}

// ---------------------------------------------------------------------------
// K0: Wih [64][768] f32 -> wp[chunk][nt][lane] = 8 f16 (frag element order:
// lane l holds W[nt*16 + (l&15)][chunk*32 + (l>>4)*8 + t], t=0..7).
// ---------------------------------------------------------------------------
__global__ __launch_bounds__(256) void pack_wih(
    const float* __restrict__ W, h8_t* __restrict__ wp)
{
    const int id = blockIdx.x * 256 + threadIdx.x;
    if (id >= 24 * 4 * 64) return;
    const int l  = id & 63;
    const int nt = (id >> 6) & 3;
    const int c  = id >> 8;
    const float* p = W + (size_t)(nt * 16 + (l & 15)) * 768 + c * 32 + (l >> 4) * 8;
    float4 r0 = *(const float4*)p;
    float4 r1 = *(const float4*)(p + 4);
    H8U u;
    u.h2[0] = pack_h2(r0.x, r0.y); u.h2[1] = pack_h2(r0.z, r0.w);
    u.h2[2] = pack_h2(r1.x, r1.y); u.h2[3] = pack_h2(r1.z, r1.w);
    wp[id] = u.h8;
}

// ---------------------------------------------------------------------------
// K1: grid 1024 x 256thr. Wave w owns rows blk*64 + w*16, cols 0..64.
// A frag: lane holds x[row = m][k = q*8 + t] (2 float4 -> cvt), depth-4.
// B frag: preconverted h8 load (coalesced, L2-resident), depth-2.
// C/D: col = lane&15, row = (lane>>4)*4 + reg.
// ---------------------------------------------------------------------------
__global__ __launch_bounds__(256) void gemm_pre0(
    const float* __restrict__ x,    // [65536][768]
    const h8_t* __restrict__ wp,    // packed Wih frags
    const float* __restrict__ bih, const float* __restrict__ bhh,
    float* __restrict__ pre0)       // [65536][64]
{
    const int tid = threadIdx.x;
    const int wv  = tid >> 6;
    const int l   = tid & 63;
    const int m   = l & 15;
    const int q   = l >> 4;
    const int rowB = blockIdx.x * 64 + wv * 16;

    const float* ax = x + (size_t)(rowB + m) * 768 + q * 8;

    float4 ar[4][2];
    h8_t   bf[2][4];

#pragma unroll
    for (int c = 0; c < 4; ++c) {
        ar[c][0] = *(const float4*)(ax + c * 32);
        ar[c][1] = *(const float4*)(ax + c * 32 + 4);
    }
#pragma unroll
    for (int c = 0; c < 2; ++c) {
        const int cb = c * 256 + l;
        bf[c][0] = wp[cb];        bf[c][1] = wp[cb + 64];
        bf[c][2] = wp[cb + 128];  bf[c][3] = wp[cb + 192];
    }

    f4_t acc[4];
#pragma unroll
    for (int nt = 0; nt < 4; ++nt)
#pragma unroll
        for (int i = 0; i < 4; ++i) acc[nt][i] = 0.0f;

#pragma unroll
    for (int it = 0; it < 24; ++it) {
        const int as = it & 3;
        const int bs = it & 1;
        H8U fa;
        fa.h2[0] = pack_h2(ar[as][0].x, ar[as][0].y);
        fa.h2[1] = pack_h2(ar[as][0].z, ar[as][0].w);
        fa.h2[2] = pack_h2(ar[as][1].x, ar[as][1].y);
        fa.h2[3] = pack_h2(ar[as][1].z, ar[as][1].w);
        h8_t fb0 = bf[bs][0], fb1 = bf[bs][1], fb2 = bf[bs][2], fb3 = bf[bs][3];

        if (it + 4 < 24) {
            const int ko = (it + 4) * 32;
            ar[as][0] = *(const float4*)(ax + ko);
            ar[as][1] = *(const float4*)(ax + ko + 4);
        }
        if (it + 2 < 24) {
            const int cb = (it + 2) * 256 + l;
            bf[bs][0] = wp[cb];        bf[bs][1] = wp[cb + 64];
            bf[bs][2] = wp[cb + 128];  bf[bs][3] = wp[cb + 192];
        }

        acc[0] = __builtin_amdgcn_mfma_f32_16x16x32_f16(fa.h8, fb0, acc[0], 0, 0, 0);
        acc[1] = __builtin_amdgcn_mfma_f32_16x16x32_f16(fa.h8, fb1, acc[1], 0, 0, 0);
        acc[2] = __builtin_amdgcn_mfma_f32_16x16x32_f16(fa.h8, fb2, acc[2], 0, 0, 0);
        acc[3] = __builtin_amdgcn_mfma_f32_16x16x32_f16(fa.h8, fb3, acc[3], 0, 0, 0);
    }

    float bn[4];
#pragma unroll
    for (int nt = 0; nt < 4; ++nt) bn[nt] = bih[nt * 16 + m] + bhh[nt * 16 + m];
#pragma unroll
    for (int i = 0; i < 4; ++i) {
        int row = rowB + q * 4 + i;
        float* pr = pre0 + (size_t)row * 64 + m;
#pragma unroll
        for (int nt = 0; nt < 4; ++nt)
            pr[nt * 16] = acc[nt][i] + bn[nt];
    }
}

// ---------------------------------------------------------------------------
// One epoch (16 steps) of a middle/top layer wave (per batch).
// Prologue: x-part for all 16 slots via MFMA; biases folded into xb scatter;
// xs read back into registers (same-wave LDS ordering).
// Steps: 8 broadcast b128 (own recurrence) + 32 fdot2 + tanh + b16 write.
// ---------------------------------------------------------------------------
__device__ __forceinline__ float layer_epoch(
    const __fp16* __restrict__ in0,   // [16][64] lower-layer slots (synced)
    __fp16* __restrict__ self0, int par,
    const h2_t* wB2, const h8_t* wX, float* __restrict__ xb,
    const float* bias4, int j)
{
    __fp16*       selfPar  = self0 + par * 1024;        // 16*64
    const __fp16* selfPrev = self0 + (par ^ 1) * 1024;
    const int mm = j & 15;
    const int q4 = j >> 4;

    // ---- x-part MFMA prologue (full 16 slots) ----
    F4H8 A0, A1;
    const __fp16* arow = in0 + mm * 64 + q4 * 8;
    A0.f = *(const float4*)arow;
    A1.f = *(const float4*)(arow + 32);

    f4_t xacc[4];
#pragma unroll
    for (int nt = 0; nt < 4; ++nt) {
#pragma unroll
        for (int i = 0; i < 4; ++i) xacc[nt][i] = 0.0f;
        xacc[nt] = __builtin_amdgcn_mfma_f32_16x16x32_f16(
            A0.h8, wX[nt * 2 + 0], xacc[nt], 0, 0, 0);
        xacc[nt] = __builtin_amdgcn_mfma_f32_16x16x32_f16(
            A1.h8, wX[nt * 2 + 1], xacc[nt], 0, 0, 0);
    }
#pragma unroll
    for (int nt = 0; nt < 4; ++nt)
#pragma unroll
        for (int i = 0; i < 4; ++i)
            xb[(q4 * 4 + i) * 64 + nt * 16 + mm] = xacc[nt][i] + bias4[nt];

    // read back own-lane xs (same-wave LDS ordering)
    float xs[16];
#pragma unroll
    for (int s = 0; s < 16; ++s) xs[s] = xb[s * 64 + j];

    // ---- 16 recurrent steps ----
    float hN = 0.0f;
#pragma unroll
    for (int s = 0; s < 16; ++s) {
        const __fp16* rc = (s == 0) ? (selfPrev + 15 * 64) : (selfPar + (s - 1) * 64);
        F4H uh[8];
#pragma unroll
        for (int qq = 0; qq < 8; ++qq) uh[qq].f = *(const float4*)(rc + qq * 8);

        float a0 = 0.f, a1 = 0.f, a2 = 0.f, a3 = 0.f;
#pragma unroll
        for (int qq = 0; qq < 8; ++qq) {
            a0 = fdot2(wB2[qq * 4 + 0], uh[qq].h[0], a0);
            a1 = fdot2(wB2[qq * 4 + 1], uh[qq].h[1], a1);
            a2 = fdot2(wB2[qq * 4 + 2], uh[qq].h[2], a2);
            a3 = fdot2(wB2[qq * 4 + 3], uh[qq].h[3], a3);
        }
        hN = tanh_fast((a0 + a1) + (a2 + a3) + xs[s]);
        selfPar[s * 64 + j] = (__fp16)hN;
    }
    return hN;
}

// ---------------------------------------------------------------------------
// Recurrence: block = 4 batch elements, 12 waves. wave w: layer g = w>>2,
// batch bi = w&3. HW round-robins waves onto the 4 SIMDs -> each SIMD holds
// ~3 independent-chain waves (latency interleaving). Epochs of 16 steps,
// ONE barrier per epoch, same parity/stagger scheme as before (per batch).
// ---------------------------------------------------------------------------
__global__ __launch_bounds__(768, 1) void rnn_fused(
    const float* __restrict__ pre0,  // [128*512][64], layer-0 biases folded in
    const float* __restrict__ Whh0,
    const float* __restrict__ Wih1, const float* __restrict__ Whh1,
    const float* __restrict__ bih1, const float* __restrict__ bhh1,
    const float* __restrict__ Wih2, const float* __restrict__ Whh2,
    const float* __restrict__ bih2, const float* __restrict__ bhh2,
    const float* __restrict__ fcw, const float* __restrict__ fcb,
    float* __restrict__ out)
{
    const int tid = threadIdx.x;
    const int w   = tid >> 6;
    const int g   = w >> 2;          // layer 0..2
    const int bi  = w & 3;           // batch within block
    const int j   = tid & 63;        // output unit
    const int b   = blockIdx.x * 4 + bi;

    __shared__ __align__(16) __fp16 hb[4][3][2][16][64];   // 48 KB
    __shared__ __align__(16) float  xb2[4][2][16][64];     // 32 KB

    // recurrent (Whh) rows packed f16, fdot2 path — all waves
    const float* WB = (g == 0) ? Whh0 : ((g == 1) ? Whh1 : Whh2);
    h2_t wB2[32];
#pragma unroll
    for (int i = 0; i < 32; ++i)
        wB2[i] = pack_h2(WB[j * 64 + 2 * i], WB[j * 64 + 2 * i + 1]);

    // Wih B-frags for the per-epoch x-MFMA (g1/g2; g0 loads dummy from Whh0)
    const float* WX = (g == 1) ? Wih1 : ((g == 2) ? Wih2 : Whh0);
    const int mm = j & 15, q4 = j >> 4;
    h8_t wX[8];
#pragma unroll
    for (int nt = 0; nt < 4; ++nt)
#pragma unroll
        for (int c = 0; c < 2; ++c) {
            const float* p = WX + (nt * 16 + mm) * 64 + c * 32 + q4 * 8;
            float4 r0 = *(const float4*)p;
            float4 r1 = *(const float4*)(p + 4);
            H8U u;
            u.h2[0] = pack_h2(r0.x, r0.y); u.h2[1] = pack_h2(r0.z, r0.w);
            u.h2[2] = pack_h2(r1.x, r1.y); u.h2[3] = pack_h2(r1.z, r1.w);
            wX[nt * 2 + c] = u.h8;
        }

    // per-lane scatter-column biases (col = nt*16 + mm), folded into xb
    float bias4[4];
#pragma unroll
    for (int nt = 0; nt < 4; ++nt) {
        const int col = nt * 16 + mm;
        bias4[nt] = (g == 1) ? (bih1[col] + bhh1[col])
                  : ((g == 2) ? (bih2[col] + bhh2[col]) : 0.0f);
    }

    // zero all of hb: 4*3*2*16*64 f16 = 12288 dwords / 768 thr = 16 each
#pragma unroll
    for (int i = 0; i < 16; ++i) ((unsigned int*)hb)[tid + 768 * i] = 0u;

    // pre0 double-buffered epoch prefetch (g0 waves)
    const size_t pbase = (size_t)b * 32768;
    float pc[16], pn[16];
    if (g == 0) {
#pragma unroll
        for (int s = 0; s < 16; ++s) pc[s] = pre0[pbase + s * 64 + j];
    }
    __syncthreads();

    float hLast = 0.0f;

    for (int e = 0; e < 34; ++e) {
        if (g == 0) {
            if (e < 32) {
                if (e < 31) {
#pragma unroll
                    for (int s = 0; s < 16; ++s)
                        pn[s] = pre0[pbase + (size_t)(e + 1) * 1024 + s * 64 + j];
                }
                const int par = e & 1;
#pragma unroll
                for (int s = 0; s < 16; ++s) {
                    const __fp16* rc = (s == 0) ? hb[bi][0][par ^ 1][15]
                                                : hb[bi][0][par][s - 1];
                    float a0 = 0.f, a1 = 0.f, a2 = 0.f, a3 = 0.f;
#pragma unroll
                    for (int qq = 0; qq < 8; ++qq) {
                        F4H u; u.f = *(const float4*)&rc[qq * 8];
                        a0 = fdot2(wB2[qq * 4 + 0], u.h[0], a0);
                        a1 = fdot2(wB2[qq * 4 + 1], u.h[1], a1);
                        a2 = fdot2(wB2[qq * 4 + 2], u.h[2], a2);
                        a3 = fdot2(wB2[qq * 4 + 3], u.h[3], a3);
                    }
                    float hN = tanh_fast((a0 + a1) + (a2 + a3) + pc[s]);
                    hb[bi][0][par][s][j] = (__fp16)hN;
                }
#pragma unroll
                for (int s = 0; s < 16; ++s) pc[s] = pn[s];
            }
        } else if (g == 1) {
            if (e >= 1 && e < 33) {
                const int par = (e - 1) & 1;
                layer_epoch(&hb[bi][0][par][0][0], &hb[bi][1][0][0][0], par,
                            wB2, wX, &xb2[bi][0][0][0], bias4, j);
            }
        } else {
            if (e >= 2) {
                const int par = e & 1;   // == (e-2)&1
                float hN = layer_epoch(&hb[bi][1][par][0][0], &hb[bi][2][0][0][0],
                                       par, wB2, wX, &xb2[bi][1][0][0], bias4, j);
                if (e == 33) hLast = hN;   // t = 511
            }
        }
        __syncthreads();
    }

    // FC epilogue on layer-2 waves (one per batch)
    if (g == 2) {
        float v = hLast * fcw[j];
#pragma unroll
        for (int m = 1; m < 64; m <<= 1) v += __shfl_xor(v, m, 64);
        if (j == 0) out[b] = v + fcb[0];
    }
}

extern "C" void kernel_launch(void* const* d_in, const int* in_sizes, int n_in,
                              void* d_out, int out_size, void* d_ws, size_t ws_size,
                              hipStream_t stream) {
    const float* x    = (const float*)d_in[0];
    const float* Wih0 = (const float*)d_in[2];
    const float* Whh0 = (const float*)d_in[3];
    const float* bih0 = (const float*)d_in[4];
    const float* bhh0 = (const float*)d_in[5];
    const float* Wih1 = (const float*)d_in[6];
    const float* Whh1 = (const float*)d_in[7];
    const float* bih1 = (const float*)d_in[8];
    const float* bhh1 = (const float*)d_in[9];
    const float* Wih2 = (const float*)d_in[10];
    const float* Whh2 = (const float*)d_in[11];
    const float* bih2 = (const float*)d_in[12];
    const float* bhh2 = (const float*)d_in[13];
    const float* fcw  = (const float*)d_in[14];
    const float* fcb  = (const float*)d_in[15];
    float* out  = (float*)d_out;
    float* pre0 = (float*)d_ws;                      // 16.78 MB fp32
    h8_t* wpack = (h8_t*)((char*)d_ws + (size_t)65536 * 64 * 4);  // 96 KB

    pack_wih<<<24, 256, 0, stream>>>(Wih0, wpack);
    gemm_pre0<<<1024, 256, 0, stream>>>(x, wpack, bih0, bhh0, pre0);
    rnn_fused<<<32, 768, 0, stream>>>(pre0, Whh0, Wih1, Whh1, bih1, bhh1,
                                      Wih2, Whh2, bih2, bhh2, fcw, fcb, out);
}

// Round 6
// 410.967 us; speedup vs baseline: 1.2355x; 1.2355x over previous
//
#include <hip/hip_runtime.h>

// ---------------------------------------------------------------------------
// RNNModel: 3-layer tanh RNN (B=128, T=512, IN=768, H=64) + FC(64->1)
// K0: pack_wih — one-shot Wih f32 -> fragment-ordered f16 (96 KB in ws).
// K1: MFMA f16 GEMM, LDS-free: wave = 16x64 C-tile, depth-6 A prefetch,
//     depth-2 packed-B prefetch (B is L2-resident).  R5 (resubmit: infra fail).
// K2: fused recurrence, R3-exact structure (R4's 4-batch/block variant
//     saturated the per-CU LDS broadcast pipe: 96 b128/step = 768cy -> 2x
//     slower; reverted). 1 batch/block, 3 waves (wave=layer), 16-step epochs,
//     x-part once per epoch via MFMA, biases folded into xb, per-step chain:
//     8 b128 rc reads -> 32 fdot2 -> tanh -> b16 write.
// ---------------------------------------------------------------------------

typedef __fp16 h2_t __attribute__((ext_vector_type(2)));
typedef __fp16 h8_t __attribute__((ext_vector_type(8)));
typedef float  f4_t __attribute__((ext_vector_type(4)));

union F4H  { float4 f; h2_t h[4]; };
union F4H8 { float4 f; h8_t h8; h2_t h2[4]; };
union H8U  { h2_t h2[4]; h8_t h8; };

__device__ __forceinline__ float fdot2(h2_t a, h2_t b, float c) {
    return __builtin_amdgcn_fdot2(a, b, c, false);
}
__device__ __forceinline__ h2_t pack_h2(float x, float y) {
    return __builtin_amdgcn_cvt_pkrtz(x, y);
}
__device__ __forceinline__ float tanh_fast(float x) {
    float e = __expf(2.0f * x);
    return 1.0f - 2.0f * __builtin_amdgcn_rcpf(e + 1.0f);
}

// ---------------------------------------------------------------------------
// K0: Wih [64][768] f32 -> wp[chunk][nt][lane] = 8 f16 (frag element order:
// lane l holds W[nt*16 + (l&15)][chunk*32 + (l>>4)*8 + t], t=0..7).
// ---------------------------------------------------------------------------
__global__ __launch_bounds__(256) void pack_wih(
    const float* __restrict__ W, h8_t* __restrict__ wp)
{
    const int id = blockIdx.x * 256 + threadIdx.x;
    if (id >= 24 * 4 * 64) return;
    const int l  = id & 63;
    const int nt = (id >> 6) & 3;
    const int c  = id >> 8;
    const float* p = W + (size_t)(nt * 16 + (l & 15)) * 768 + c * 32 + (l >> 4) * 8;
    float4 r0 = *(const float4*)p;
    float4 r1 = *(const float4*)(p + 4);
    H8U u;
    u.h2[0] = pack_h2(r0.x, r0.y); u.h2[1] = pack_h2(r0.z, r0.w);
    u.h2[2] = pack_h2(r1.x, r1.y); u.h2[3] = pack_h2(r1.z, r1.w);
    wp[id] = u.h8;
}

// ---------------------------------------------------------------------------
// K1: grid 1024 x 256thr. Wave w owns rows blk*64 + w*16, cols 0..64.
// A frag: lane holds x[row = m][k = q*8 + t] (2 float4 -> cvt), depth-6.
// B frag: preconverted h8 load (coalesced, L2-resident), depth-2.
// C/D: col = lane&15, row = (lane>>4)*4 + reg.
// ---------------------------------------------------------------------------
__global__ __launch_bounds__(256) void gemm_pre0(
    const float* __restrict__ x,    // [65536][768]
    const h8_t* __restrict__ wp,    // packed Wih frags
    const float* __restrict__ bih, const float* __restrict__ bhh,
    float* __restrict__ pre0)       // [65536][64]
{
    const int tid = threadIdx.x;
    const int wv  = tid >> 6;
    const int l   = tid & 63;
    const int m   = l & 15;
    const int q   = l >> 4;
    const int rowB = blockIdx.x * 64 + wv * 16;

    const float* ax = x + (size_t)(rowB + m) * 768 + q * 8;

    float4 ar[6][2];
    h8_t   bf[2][4];

#pragma unroll
    for (int c = 0; c < 6; ++c) {
        ar[c][0] = *(const float4*)(ax + c * 32);
        ar[c][1] = *(const float4*)(ax + c * 32 + 4);
    }
#pragma unroll
    for (int c = 0; c < 2; ++c) {
        const int cb = c * 256 + l;
        bf[c][0] = wp[cb];        bf[c][1] = wp[cb + 64];
        bf[c][2] = wp[cb + 128];  bf[c][3] = wp[cb + 192];
    }

    f4_t acc[4];
#pragma unroll
    for (int nt = 0; nt < 4; ++nt)
#pragma unroll
        for (int i = 0; i < 4; ++i) acc[nt][i] = 0.0f;

#pragma unroll
    for (int it = 0; it < 24; ++it) {
        const int as = it % 6;
        const int bs = it & 1;
        H8U fa;
        fa.h2[0] = pack_h2(ar[as][0].x, ar[as][0].y);
        fa.h2[1] = pack_h2(ar[as][0].z, ar[as][0].w);
        fa.h2[2] = pack_h2(ar[as][1].x, ar[as][1].y);
        fa.h2[3] = pack_h2(ar[as][1].z, ar[as][1].w);
        h8_t fb0 = bf[bs][0], fb1 = bf[bs][1], fb2 = bf[bs][2], fb3 = bf[bs][3];

        if (it + 6 < 24) {
            const int ko = (it + 6) * 32;
            ar[as][0] = *(const float4*)(ax + ko);
            ar[as][1] = *(const float4*)(ax + ko + 4);
        }
        if (it + 2 < 24) {
            const int cb = (it + 2) * 256 + l;
            bf[bs][0] = wp[cb];        bf[bs][1] = wp[cb + 64];
            bf[bs][2] = wp[cb + 128];  bf[bs][3] = wp[cb + 192];
        }

        acc[0] = __builtin_amdgcn_mfma_f32_16x16x32_f16(fa.h8, fb0, acc[0], 0, 0, 0);
        acc[1] = __builtin_amdgcn_mfma_f32_16x16x32_f16(fa.h8, fb1, acc[1], 0, 0, 0);
        acc[2] = __builtin_amdgcn_mfma_f32_16x16x32_f16(fa.h8, fb2, acc[2], 0, 0, 0);
        acc[3] = __builtin_amdgcn_mfma_f32_16x16x32_f16(fa.h8, fb3, acc[3], 0, 0, 0);
    }

    float bn[4];
#pragma unroll
    for (int nt = 0; nt < 4; ++nt) bn[nt] = bih[nt * 16 + m] + bhh[nt * 16 + m];
#pragma unroll
    for (int i = 0; i < 4; ++i) {
        int row = rowB + q * 4 + i;
        float* pr = pre0 + (size_t)row * 64 + m;
#pragma unroll
        for (int nt = 0; nt < 4; ++nt)
            pr[nt * 16] = acc[nt][i] + bn[nt];
    }
}

// ---------------------------------------------------------------------------
// One epoch (16 steps) of a middle/top layer wave.
// Prologue: x-part for all 16 slots via MFMA; biases folded into xb scatter;
// xs read back into registers (same-wave LDS ordering).
// Steps: 8 broadcast b128 (own recurrence) + 32 fdot2 + tanh + b16 write.
// ---------------------------------------------------------------------------
__device__ __forceinline__ float layer_epoch(
    const __fp16* __restrict__ in0,   // [16][64] lower-layer slots (synced)
    __fp16* __restrict__ self0, int par,
    const h2_t* wB2, const h8_t* wX, float* __restrict__ xb,
    const float* bias4, int j)
{
    __fp16*       selfPar  = self0 + par * 1024;        // 16*64
    const __fp16* selfPrev = self0 + (par ^ 1) * 1024;
    const int mm = j & 15;
    const int q4 = j >> 4;

    // ---- x-part MFMA prologue (full 16 slots) ----
    F4H8 A0, A1;
    const __fp16* arow = in0 + mm * 64 + q4 * 8;
    A0.f = *(const float4*)arow;
    A1.f = *(const float4*)(arow + 32);

    f4_t xacc[4];
#pragma unroll
    for (int nt = 0; nt < 4; ++nt) {
#pragma unroll
        for (int i = 0; i < 4; ++i) xacc[nt][i] = 0.0f;
        xacc[nt] = __builtin_amdgcn_mfma_f32_16x16x32_f16(
            A0.h8, wX[nt * 2 + 0], xacc[nt], 0, 0, 0);
        xacc[nt] = __builtin_amdgcn_mfma_f32_16x16x32_f16(
            A1.h8, wX[nt * 2 + 1], xacc[nt], 0, 0, 0);
    }
#pragma unroll
    for (int nt = 0; nt < 4; ++nt)
#pragma unroll
        for (int i = 0; i < 4; ++i)
            xb[(q4 * 4 + i) * 64 + nt * 16 + mm] = xacc[nt][i] + bias4[nt];

    // read back own-lane xs (same-wave LDS ordering)
    float xs[16];
#pragma unroll
    for (int s = 0; s < 16; ++s) xs[s] = xb[s * 64 + j];

    // ---- 16 recurrent steps ----
    float hN = 0.0f;
#pragma unroll
    for (int s = 0; s < 16; ++s) {
        const __fp16* rc = (s == 0) ? (selfPrev + 15 * 64) : (selfPar + (s - 1) * 64);
        F4H uh[8];
#pragma unroll
        for (int qq = 0; qq < 8; ++qq) uh[qq].f = *(const float4*)(rc + qq * 8);

        float a0 = 0.f, a1 = 0.f, a2 = 0.f, a3 = 0.f;
#pragma unroll
        for (int qq = 0; qq < 8; ++qq) {
            a0 = fdot2(wB2[qq * 4 + 0], uh[qq].h[0], a0);
            a1 = fdot2(wB2[qq * 4 + 1], uh[qq].h[1], a1);
            a2 = fdot2(wB2[qq * 4 + 2], uh[qq].h[2], a2);
            a3 = fdot2(wB2[qq * 4 + 3], uh[qq].h[3], a3);
        }
        hN = tanh_fast((a0 + a1) + (a2 + a3) + xs[s]);
        selfPar[s * 64 + j] = (__fp16)hN;
    }
    return hN;
}

// ---------------------------------------------------------------------------
// Recurrence: block = batch element, 3 waves (wave g = layer g).
// Epochs of S=16 steps; ONE barrier per epoch. hb[layer][parity][slot][unit]:
// wave g writes slots of epoch e with parity e_g&1; consumer reads them
// next epoch (opposite parity) — WAR separated by exactly one barrier.
// xb2[g-1] is written+read by the SAME wave within an epoch (lgkm ordering).
// ---------------------------------------------------------------------------
__global__ __launch_bounds__(192, 1) void rnn_fused(
    const float* __restrict__ pre0,  // [128*512][64], layer-0 biases folded in
    const float* __restrict__ Whh0,
    const float* __restrict__ Wih1, const float* __restrict__ Whh1,
    const float* __restrict__ bih1, const float* __restrict__ bhh1,
    const float* __restrict__ Wih2, const float* __restrict__ Whh2,
    const float* __restrict__ bih2, const float* __restrict__ bhh2,
    const float* __restrict__ fcw, const float* __restrict__ fcb,
    float* __restrict__ out)
{
    const int tid = threadIdx.x;
    const int g   = tid >> 6;        // layer 0..2
    const int j   = tid & 63;        // output unit
    const int b   = blockIdx.x;

    __shared__ __align__(16) __fp16 hb[3][2][16][64];
    __shared__ __align__(16) float  xb2[2][16][64];

    // recurrent (Whh) rows packed f16, fdot2 path — all waves
    const float* WB = (g == 0) ? Whh0 : ((g == 1) ? Whh1 : Whh2);
    h2_t wB2[32];
#pragma unroll
    for (int i = 0; i < 32; ++i)
        wB2[i] = pack_h2(WB[j * 64 + 2 * i], WB[j * 64 + 2 * i + 1]);

    // Wih B-frags for the per-epoch x-MFMA (g1/g2; g0 loads dummy from Whh0)
    const float* WX = (g == 1) ? Wih1 : ((g == 2) ? Wih2 : Whh0);
    const int mm = j & 15, q4 = j >> 4;
    h8_t wX[8];
#pragma unroll
    for (int nt = 0; nt < 4; ++nt)
#pragma unroll
        for (int c = 0; c < 2; ++c) {
            const float* p = WX + (nt * 16 + mm) * 64 + c * 32 + q4 * 8;
            float4 r0 = *(const float4*)p;
            float4 r1 = *(const float4*)(p + 4);
            H8U u;
            u.h2[0] = pack_h2(r0.x, r0.y); u.h2[1] = pack_h2(r0.z, r0.w);
            u.h2[2] = pack_h2(r1.x, r1.y); u.h2[3] = pack_h2(r1.z, r1.w);
            wX[nt * 2 + c] = u.h8;
        }

    // per-lane scatter-column biases (col = nt*16 + mm), folded into xb
    float bias4[4];
#pragma unroll
    for (int nt = 0; nt < 4; ++nt) {
        const int col = nt * 16 + mm;
        bias4[nt] = (g == 1) ? (bih1[col] + bhh1[col])
                  : ((g == 2) ? (bih2[col] + bhh2[col]) : 0.0f);
    }

    // zero all of hb: 3*2*16*64 f16 = 3072 dwords / 192 thr = 16 each
#pragma unroll
    for (int i = 0; i < 16; ++i) ((unsigned int*)hb)[tid + 192 * i] = 0u;

    // pre0 double-buffered epoch prefetch (wave 0)
    const size_t pbase = (size_t)b * 32768;
    float pc[16], pn[16];
    if (g == 0) {
#pragma unroll
        for (int s = 0; s < 16; ++s) pc[s] = pre0[pbase + s * 64 + j];
    }
    __syncthreads();

    float hLast = 0.0f;

    for (int e = 0; e < 34; ++e) {
        if (g == 0) {
            if (e < 32) {
                if (e < 31) {
#pragma unroll
                    for (int s = 0; s < 16; ++s)
                        pn[s] = pre0[pbase + (size_t)(e + 1) * 1024 + s * 64 + j];
                }
                const int par = e & 1;
#pragma unroll
                for (int s = 0; s < 16; ++s) {
                    const __fp16* rc = (s == 0) ? hb[0][par ^ 1][15] : hb[0][par][s - 1];
                    float a0 = 0.f, a1 = 0.f, a2 = 0.f, a3 = 0.f;
#pragma unroll
                    for (int qq = 0; qq < 8; ++qq) {
                        F4H u; u.f = *(const float4*)&rc[qq * 8];
                        a0 = fdot2(wB2[qq * 4 + 0], u.h[0], a0);
                        a1 = fdot2(wB2[qq * 4 + 1], u.h[1], a1);
                        a2 = fdot2(wB2[qq * 4 + 2], u.h[2], a2);
                        a3 = fdot2(wB2[qq * 4 + 3], u.h[3], a3);
                    }
                    float hN = tanh_fast((a0 + a1) + (a2 + a3) + pc[s]);
                    hb[0][par][s][j] = (__fp16)hN;
                }
#pragma unroll
                for (int s = 0; s < 16; ++s) pc[s] = pn[s];
            }
        } else if (g == 1) {
            if (e >= 1 && e < 33) {
                const int par = (e - 1) & 1;
                layer_epoch(&hb[0][par][0][0], &hb[1][0][0][0], par,
                            wB2, wX, &xb2[0][0][0], bias4, j);
            }
        } else {
            if (e >= 2) {
                const int par = e & 1;   // == (e-2)&1
                float hN = layer_epoch(&hb[1][par][0][0], &hb[2][0][0][0], par,
                                       wB2, wX, &xb2[1][0][0], bias4, j);
                if (e == 33) hLast = hN;   // t = 511
            }
        }
        __syncthreads();
    }

    // FC epilogue on wave 2
    if (g == 2) {
        float v = hLast * fcw[j];
#pragma unroll
        for (int m = 1; m < 64; m <<= 1) v += __shfl_xor(v, m, 64);
        if (j == 0) out[b] = v + fcb[0];
    }
}

extern "C" void kernel_launch(void* const* d_in, const int* in_sizes, int n_in,
                              void* d_out, int out_size, void* d_ws, size_t ws_size,
                              hipStream_t stream) {
    const float* x    = (const float*)d_in[0];
    const float* Wih0 = (const float*)d_in[2];
    const float* Whh0 = (const float*)d_in[3];
    const float* bih0 = (const float*)d_in[4];
    const float* bhh0 = (const float*)d_in[5];
    const float* Wih1 = (const float*)d_in[6];
    const float* Whh1 = (const float*)d_in[7];
    const float* bih1 = (const float*)d_in[8];
    const float* bhh1 = (const float*)d_in[9];
    const float* Wih2 = (const float*)d_in[10];
    const float* Whh2 = (const float*)d_in[11];
    const float* bih2 = (const float*)d_in[12];
    const float* bhh2 = (const float*)d_in[13];
    const float* fcw  = (const float*)d_in[14];
    const float* fcb  = (const float*)d_in[15];
    float* out  = (float*)d_out;
    float* pre0 = (float*)d_ws;                      // 16.78 MB fp32
    h8_t* wpack = (h8_t*)((char*)d_ws + (size_t)65536 * 64 * 4);  // 96 KB

    pack_wih<<<24, 256, 0, stream>>>(Wih0, wpack);
    gemm_pre0<<<1024, 256, 0, stream>>>(x, wpack, bih0, bhh0, pre0);
    rnn_fused<<<128, 192, 0, stream>>>(pre0, Whh0, Wih1, Whh1, bih1, bhh1,
                                       Wih2, Whh2, bih2, bhh2, fcw, fcb, out);
}